// Round 3
// baseline (1209.931 us; speedup 1.0000x reference)
//
#include <hip/hip_runtime.h>
#include <math.h>

#define F_IN 512
#define HID  16
#define NCLS 40
#define NPB  128      // nodes per bucket (c >> 7)
#define NPW  1024     // partition workgroups
#define MAXBUK 1024
#define CHCAP 3200    // max edges per k_part chunk staged in LDS

typedef __attribute__((ext_vector_type(8))) short short8;
typedef __attribute__((ext_vector_type(4))) float floatx4;

// ---------- bf16 helpers (RNE used for W staging only) ----------
__device__ __forceinline__ unsigned short bf16_rne(float f) {
    unsigned u = __float_as_uint(f);
    u += 0x7fffu + ((u >> 16) & 1u);
    return (unsigned short)(u >> 16);
}
__device__ __forceinline__ float bf16_f32(unsigned short s) {
    return __uint_as_float(((unsigned)s) << 16);
}

// ---------- Phase A: per-WG bucket histogram (LDS atomics) + wdeg=1 init ----------
__global__ void k_hist(const int* __restrict__ col, int* __restrict__ g_hist,
                       float* __restrict__ wdeg,
                       int E, int chunk, int nbuk, int N, int chunkN) {
    __shared__ int h[MAXBUK];
    for (int i = threadIdx.x; i < nbuk; i += 256) h[i] = 0;
    // self-loop weight init (independent of h; k_part adds edge weights later)
    {
        int s = blockIdx.x * chunkN;
        int e = s + chunkN; if (e > N) e = N;
        for (int i = s + threadIdx.x; i < e; i += 256) wdeg[i] = 1.0f;
    }
    __syncthreads();
    int s = blockIdx.x * chunk;
    int e = s + chunk; if (e > E) e = E;
    for (int j = s + threadIdx.x; j < e; j += 256)
        atomicAdd(&h[col[j] >> 7], 1);
    __syncthreads();
    for (int i = threadIdx.x; i < nbuk; i += 256)
        g_hist[(size_t)blockIdx.x * nbuk + i] = h[i];
}

// ---------- fused: per-(wg,bucket) BASE-RELATIVE offsets + per-bucket totals ----------
__global__ void k_offs2(int* __restrict__ g_hist, int* __restrict__ tot,
                        int nbuk, int W) {
    __shared__ int tsum[256];
    int b = blockIdx.x, t = threadIdx.x;
    int v[4]; int sum = 0;
    #pragma unroll
    for (int i = 0; i < 4; ++i) {
        int w = 4 * t + i;
        v[i] = (w < W) ? g_hist[(size_t)w * nbuk + b] : 0;
        sum += v[i];
    }
    tsum[t] = sum; __syncthreads();
    int run = sum;
    for (int off = 1; off < 256; off <<= 1) {
        int a = (t >= off) ? tsum[t - off] : 0;
        __syncthreads(); tsum[t] += a; __syncthreads();
    }
    int excl = tsum[t] - run;
    #pragma unroll
    for (int i = 0; i < 4; ++i) {
        int w = 4 * t + i;
        if (w < W) { g_hist[(size_t)w * nbuk + b] = excl; excl += v[i]; }
    }
    if (t == 255) tot[b] = tsum[255];
}

// ---------- exclusive scan of totals -> bucket base ----------
__global__ void k_base(const int* __restrict__ tot, int* __restrict__ base,
                       int nbuk, int E) {
    __shared__ int s[1024];
    int t = threadIdx.x;
    int v = (t < nbuk) ? tot[t] : 0;
    s[t] = v; __syncthreads();
    for (int off = 1; off < 1024; off <<= 1) {
        int a = (t >= off) ? s[t - off] : 0;
        __syncthreads(); s[t] += a; __syncthreads();
    }
    if (t < nbuk) base[t] = s[t] - v;
    if (t == 0) base[nbuk] = E;
}

// ---------- Phase C: chunk counting-sort in LDS -> bucket-run-ordered flush ----------
// Also accumulates weighted degree via global float atomics (L2-resident).
// record: x = r | (local_c << 17), y = bits(w)
__global__ void k_part(const int* __restrict__ row, const int* __restrict__ col,
                       const float* __restrict__ wt, const int* __restrict__ g_hist,
                       const int* __restrict__ base, uint2* __restrict__ sedge,
                       float* __restrict__ wdeg, int E, int chunk, int nbuk) {
    __shared__ uint2 recs[CHCAP];
    __shared__ unsigned short bks[CHCAP];
    __shared__ int lcnt[MAXBUK];   // counts -> then delta = globalBase - localBase
    __shared__ int lcur[MAXBUK];   // atomic local slot cursor
    __shared__ int tsum[256];
    int t = threadIdx.x;
    int s = blockIdx.x * chunk;
    int e = s + chunk; if (e > E) e = E;
    int n = e - s;
    for (int i = t; i < nbuk; i += 256) lcnt[i] = 0;
    __syncthreads();

    if (n <= CHCAP) {
        for (int j = s + t; j < e; j += 256)
            atomicAdd(&lcnt[col[j] >> 7], 1);
        __syncthreads();
        int c[4]; int sum = 0;
        #pragma unroll
        for (int i = 0; i < 4; ++i) {
            int bb = 4 * t + i;
            c[i] = (bb < nbuk) ? lcnt[bb] : 0;
            sum += c[i];
        }
        tsum[t] = sum; __syncthreads();
        int run = sum;
        for (int off = 1; off < 256; off <<= 1) {
            int a = (t >= off) ? tsum[t - off] : 0;
            __syncthreads(); tsum[t] += a; __syncthreads();
        }
        int excl = tsum[t] - run;
        #pragma unroll
        for (int i = 0; i < 4; ++i) {
            int bb = 4 * t + i;
            if (bb < nbuk) {
                lcur[bb] = excl;
                int ob = g_hist[(size_t)blockIdx.x * nbuk + bb] + base[bb];
                lcnt[bb] = ob - excl;          // delta: slot -> global index
                excl += c[i];
            }
        }
        __syncthreads();
        for (int j = s + t; j < e; j += 256) {
            int r = row[j], cc = col[j];
            float wv = wt[j];
            int b = cc >> 7;
            int slot = atomicAdd(&lcur[b], 1);
            recs[slot] = make_uint2((unsigned)r | ((unsigned)(cc & (NPB - 1)) << 17),
                                    __float_as_uint(wv));
            bks[slot] = (unsigned short)b;
            atomicAdd(&wdeg[cc], wv);
        }
        __syncthreads();
        for (int i = t; i < n; i += 256) {
            int b = bks[i];
            sedge[lcnt[b] + i] = recs[i];
        }
    } else {
        // fallback: direct scatter (not hit at E=3.2M)
        for (int i = t; i < nbuk; i += 256)
            lcur[i] = g_hist[(size_t)blockIdx.x * nbuk + i] + base[i];
        __syncthreads();
        for (int j = s + t; j < e; j += 256) {
            int r = row[j], cc = col[j];
            float wv = wt[j];
            int b = cc >> 7;
            int pos = atomicAdd(&lcur[b], 1);
            sedge[pos] = make_uint2((unsigned)r | ((unsigned)(cc & (NPB - 1)) << 17),
                                    __float_as_uint(wv));
            atomicAdd(&wdeg[cc], wv);
        }
    }
}

// ---------- h1_hat = dis * (x @ W1) via 16x16x32 bf16 MFMA, hi/lo trunc split ----------
__global__ void k_xw1_mfma(const float* __restrict__ x, const float* __restrict__ W1,
                           const float* __restrict__ wdeg, float* __restrict__ h1,
                           int N, int nTiles) {
    __shared__ unsigned short wh[HID][F_IN + 8];
    __shared__ unsigned short wl[HID][F_IN + 8];
    for (int f = threadIdx.x; f < F_IN * HID; f += 256) {
        int k = f >> 4, h = f & 15;
        float v = W1[f];
        unsigned short hhi = bf16_rne(v);
        float rem = v - bf16_f32(hhi);
        wh[h][k] = hhi;
        wl[h][k] = (unsigned short)(__float_as_uint(rem) >> 16);
    }
    __syncthreads();

    int wave = threadIdx.x >> 6;
    int lane = threadIdx.x & 63;
    int tile = blockIdx.x * 4 + wave;
    if (tile >= nTiles) return;

    int m    = lane & 15;
    int quad = lane >> 4;
    int node = tile * 16 + m;
    if (node >= N) node = N - 1;
    const float* xr = x + (size_t)node * F_IN;

    floatx4 acc = {0.f, 0.f, 0.f, 0.f};

    #pragma unroll 4
    for (int s = 0; s < F_IN / 32; ++s) {
        int k0 = s * 32 + quad * 8;
        float4 v0 = *(const float4*)(xr + k0);
        float4 v1 = *(const float4*)(xr + k0 + 4);
        float xv[8] = {v0.x, v0.y, v0.z, v0.w, v1.x, v1.y, v1.z, v1.w};
        short8 ah, al;
        #pragma unroll
        for (int j = 0; j < 8; ++j) {
            unsigned u = __float_as_uint(xv[j]);
            ah[j] = (short)(u >> 16);                       // truncated hi
            float rem = xv[j] - __uint_as_float(u & 0xffff0000u);
            al[j] = (short)(__float_as_uint(rem) >> 16);    // truncated lo
        }
        short8 bh = *(const short8*)&wh[m][k0];
        short8 bl = *(const short8*)&wl[m][k0];
        acc = __builtin_amdgcn_mfma_f32_16x16x32_bf16(ah, bh, acc, 0, 0, 0);
        acc = __builtin_amdgcn_mfma_f32_16x16x32_bf16(ah, bl, acc, 0, 0, 0);
        acc = __builtin_amdgcn_mfma_f32_16x16x32_bf16(al, bh, acc, 0, 0, 0);
    }

    int h = lane & 15;
    #pragma unroll
    for (int r = 0; r < 4; ++r) {
        int nrow = tile * 16 + quad * 4 + r;
        if (nrow < N) {
            float d = rsqrtf(wdeg[nrow]);
            h1[(size_t)nrow * HID + h] = d * acc[r];
        }
    }
}

// ---------- bucket-LDS aggregation (replaces k_sort + k_agg2 [+ k_final]) ----------
// One WG per bucket. acc[lc][h] accumulated with LDS float atomics over the
// bucket's dense edge run in sedge. src holds PRE-SCALED hhat = dis*h.
// out==null : dst = (postscale? d:1) * relu?(d*(acc+hhat_self)+bias)
// out!=null : fused z2 -> log_softmax(z2 @ W2 + b2) -> out
__global__ void k_agg_b(const uint2* __restrict__ sedge, const int* __restrict__ base,
                        const float* __restrict__ wdeg, const float* __restrict__ src,
                        const float* __restrict__ bias,
                        const float* __restrict__ W2, const float* __restrict__ b2,
                        float* __restrict__ dst, float* __restrict__ out,
                        int N, int relu, int postscale) {
    __shared__ float acc[NPB][HID + 1];   // +1 pad: softmax reads stride-17 -> no 16-way conflict
    __shared__ float w2s[HID * NCLS];
    __shared__ float b2s[NCLS];
    int b = blockIdx.x, t = threadIdx.x;
    for (int i = t; i < NPB * (HID + 1); i += 256) ((float*)acc)[i] = 0.f;
    if (out) {
        for (int f = t; f < HID * NCLS; f += 256) w2s[f] = W2[f];
        if (t < NCLS) b2s[t] = b2[t];
    }
    __syncthreads();

    int s = base[b], e = base[b + 1];
    int h = t & 15;
    int j = s + (t >> 4);
    for (; j + 48 < e; j += 64) {
        uint2 r0 = sedge[j];
        uint2 r1 = sedge[j + 16];
        uint2 r2 = sedge[j + 32];
        uint2 r3 = sedge[j + 48];
        float v0 = __uint_as_float(r0.y) * src[(size_t)(r0.x & 0x1FFFF) * HID + h];
        float v1 = __uint_as_float(r1.y) * src[(size_t)(r1.x & 0x1FFFF) * HID + h];
        float v2 = __uint_as_float(r2.y) * src[(size_t)(r2.x & 0x1FFFF) * HID + h];
        float v3 = __uint_as_float(r3.y) * src[(size_t)(r3.x & 0x1FFFF) * HID + h];
        atomicAdd(&acc[r0.x >> 17][h], v0);
        atomicAdd(&acc[r1.x >> 17][h], v1);
        atomicAdd(&acc[r2.x >> 17][h], v2);
        atomicAdd(&acc[r3.x >> 17][h], v3);
    }
    for (; j < e; j += 16) {
        uint2 r = sedge[j];
        float v = __uint_as_float(r.y) * src[(size_t)(r.x & 0x1FFFF) * HID + h];
        atomicAdd(&acc[r.x >> 17][h], v);
    }
    __syncthreads();

    if (!out) {
        for (int idx = t; idx < NPB * HID; idx += 256) {
            int lc = idx >> 4, hh = idx & 15;
            int n = b * NPB + lc;
            if (n < N) {
                float d = rsqrtf(wdeg[n]);
                float v = d * (acc[lc][hh] + src[(size_t)n * HID + hh]);
                if (bias) v += bias[hh];
                if (relu) v = v > 0.f ? v : 0.f;
                if (postscale) v *= d;
                dst[(size_t)n * HID + hh] = v;
            }
        }
    } else {
        // finish z2 in place (each thread reads/writes only its own element)
        for (int idx = t; idx < NPB * HID; idx += 256) {
            int lc = idx >> 4, hh = idx & 15;
            int n = b * NPB + lc;
            float v = 0.f;
            if (n < N) {
                float d = rsqrtf(wdeg[n]);
                v = d * (acc[lc][hh] + src[(size_t)n * HID + hh]);
            }
            acc[lc][hh] = v;
        }
        __syncthreads();
        // 2 threads per node, 20 classes each; pair-reduce via shfl_xor(1)
        int lc = t >> 1;
        int half = t & 1;
        int n = b * NPB + lc;
        float a[HID];
        #pragma unroll
        for (int q = 0; q < HID; ++q) a[q] = acc[lc][q];
        float y[NCLS / 2];
        #pragma unroll
        for (int c = 0; c < NCLS / 2; ++c) y[c] = b2s[half * (NCLS / 2) + c];
        #pragma unroll
        for (int q = 0; q < HID; ++q) {
            float av = a[q];
            #pragma unroll
            for (int c = 0; c < NCLS / 2; ++c)
                y[c] = fmaf(av, w2s[q * NCLS + half * (NCLS / 2) + c], y[c]);
        }
        float m = y[0];
        #pragma unroll
        for (int c = 1; c < NCLS / 2; ++c) m = fmaxf(m, y[c]);
        m = fmaxf(m, __shfl_xor(m, 1));
        float sum = 0.f;
        #pragma unroll
        for (int c = 0; c < NCLS / 2; ++c) sum += expf(y[c] - m);
        sum += __shfl_xor(sum, 1);
        float bse = m + logf(sum);
        if (n < N) {
            float* op = out + (size_t)n * NCLS + half * (NCLS / 2);
            #pragma unroll
            for (int c = 0; c < NCLS / 2; ++c) op[c] = y[c] - bse;
        }
    }
}

// ---------- launch ----------
extern "C" void kernel_launch(void* const* d_in, const int* in_sizes, int n_in,
                              void* d_out, int out_size, void* d_ws, size_t ws_size,
                              hipStream_t stream) {
    const float* x  = (const float*)d_in[0];
    const int*   ei = (const int*)d_in[1];
    const float* ew = (const float*)d_in[2];
    const float* W1 = (const float*)d_in[3];
    const float* b1 = (const float*)d_in[4];
    const float* W2 = (const float*)d_in[5];
    const float* b2 = (const float*)d_in[6];
    float* out = (float*)d_out;

    int N = in_sizes[0] / F_IN;      // 100000
    int E = in_sizes[2];             // 3200000
    const int* row = ei;
    const int* col = ei + E;

    int nbuk   = (N + NPB - 1) / NPB;        // 782
    int chunk  = (E + NPW - 1) / NPW;        // 3125
    int chunkN = (N + NPW - 1) / NPW;        // 98

    // workspace layout
    char* w = (char*)d_ws;
    uint2* sedge  = (uint2*)w;                     size_t off = (size_t)E * 8;
    float* A      = (float*)(w + off);             off += (size_t)N * HID * 4;
    float* Bb     = (float*)(w + off);             off += (size_t)N * HID * 4;
    float* wdeg   = (float*)(w + off);             off += (size_t)N * 4;
    int*   g_hist = (int*)(w + off);               off += (size_t)NPW * nbuk * 4;
    int*   tot    = (int*)(w + off);               off += (size_t)nbuk * 4;
    int*   base   = (int*)(w + off);               off += (size_t)(nbuk + 1) * 4;

    dim3 blk(256);

    // partition build (bucket level) + weighted degree
    k_hist<<<dim3(NPW), blk, 0, stream>>>(col, g_hist, wdeg, E, chunk, nbuk, N, chunkN);
    k_offs2<<<dim3(nbuk), blk, 0, stream>>>(g_hist, tot, nbuk, NPW);
    k_base<<<dim3(1), dim3(1024), 0, stream>>>(tot, base, nbuk, E);
    k_part<<<dim3(NPW), blk, 0, stream>>>(row, col, ew, g_hist, base, sedge, wdeg, E, chunk, nbuk);

    // h1_hat = dis * (x @ W1) (MFMA)
    int nTiles = (N + 15) / 16;
    int gT = (nTiles + 3) / 4;
    k_xw1_mfma<<<dim3(gT), blk, 0, stream>>>(x, W1, wdeg, A, N, nTiles);

    // pass 1: h2_hat = dis*relu(dis*(agg+self)+b1); pass 2: fused z2 + log_softmax
    k_agg_b<<<dim3(nbuk), blk, 0, stream>>>(sedge, base, wdeg, A, b1,
                                            (const float*)nullptr, (const float*)nullptr,
                                            Bb, (float*)nullptr, N, 1, 1);
    k_agg_b<<<dim3(nbuk), blk, 0, stream>>>(sedge, base, wdeg, Bb, (const float*)nullptr,
                                            W2, b2, (float*)nullptr, out, N, 0, 0);
}

// Round 5
// 619.101 us; speedup vs baseline: 1.9543x; 1.9543x over previous
//
#include <hip/hip_runtime.h>
#include <math.h>

#define F_IN 512
#define HID  16
#define NCLS 40
#define NPB  128      // nodes per bucket (c >> 7)
#define NPW  1024     // partition workgroups
#define MAXBUK 1024
#define CHCAP 3200    // max edges per k_part chunk staged in LDS
#define SCAP  4608    // max edges per bucket staged in LDS in k_sort

typedef __attribute__((ext_vector_type(8))) short short8;
typedef __attribute__((ext_vector_type(4))) float floatx4;

// ---------- bf16 helpers ----------
__device__ __forceinline__ unsigned short bf16_rne(float f) {
    unsigned u = __float_as_uint(f);
    u += 0x7fffu + ((u >> 16) & 1u);
    return (unsigned short)(u >> 16);
}
__device__ __forceinline__ float bf16_f32(unsigned short s) {
    return __uint_as_float(((unsigned)s) << 16);
}

// ---------- zero the bucket-total array (graph-capture-safe, no hipMemset) ----------
__global__ void k_zero(int* __restrict__ p, int n) {
    int i = blockIdx.x * 256 + threadIdx.x;
    if (i < n) p[i] = 0;
}

// ---------- Phase A: per-WG LDS histogram -> global bucket totals ----------
__global__ void k_hist(const int* __restrict__ col, int* __restrict__ tot,
                       int E, int chunk, int nbuk) {
    __shared__ int h[MAXBUK];
    for (int i = threadIdx.x; i < nbuk; i += 256) h[i] = 0;
    __syncthreads();
    int s = blockIdx.x * chunk;
    int e = s + chunk; if (e > E) e = E;
    for (int j = s + threadIdx.x; j < e; j += 256)
        atomicAdd(&h[col[j] >> 7], 1);
    __syncthreads();
    for (int i = threadIdx.x; i < nbuk; i += 256)
        if (h[i]) atomicAdd(&tot[i], h[i]);
}

// ---------- exclusive scan of totals -> bucket base (+ init reservation cursors) ----------
__global__ void k_base(const int* __restrict__ tot, int* __restrict__ base,
                       int* __restrict__ gcur, int nbuk, int E) {
    __shared__ int s[1024];
    int t = threadIdx.x;
    int v = (t < nbuk) ? tot[t] : 0;
    s[t] = v; __syncthreads();
    for (int off = 1; off < 1024; off <<= 1) {
        int a = (t >= off) ? s[t - off] : 0;
        __syncthreads(); s[t] += a; __syncthreads();
    }
    if (t < nbuk) {
        int b = s[t] - v;
        base[t] = b;
        gcur[t] = b;
    }
    if (t == 0) base[nbuk] = E;
}

// ---------- Phase C: chunk counting-sort in LDS + per-bucket run reservation ----------
// Each WG groups its chunk by bucket in LDS, reserves one contiguous run per
// non-empty bucket via a single atomicAdd(&gcur[b], cnt), flushes coalesced.
// Intra-bucket order is nondeterministic (harmless: k_sort re-bins per node).
// record: x = r | (local_c << 17), y = bits(w)
__global__ void k_part(const int* __restrict__ row, const int* __restrict__ col,
                       const float* __restrict__ wt, int* __restrict__ gcur,
                       uint2* __restrict__ sedge, int E, int chunk, int nbuk) {
    __shared__ uint2 recs[CHCAP];
    __shared__ unsigned short bks[CHCAP];
    __shared__ int lcnt[MAXBUK];   // hist -> then delta = reservedBase - localBase
    __shared__ int lcur[MAXBUK];   // local slot cursor
    __shared__ int tsum[256];
    int t = threadIdx.x;
    int s = blockIdx.x * chunk;
    int e = s + chunk; if (e > E) e = E;
    int n = e - s;
    if (n <= 0) return;
    for (int i = t; i < nbuk; i += 256) lcnt[i] = 0;
    __syncthreads();

    if (n <= CHCAP) {
        // local histogram
        for (int j = s + t; j < e; j += 256)
            atomicAdd(&lcnt[col[j] >> 7], 1);
        __syncthreads();
        // blocked exclusive scan over nbuk bins (4 consecutive bins/thread)
        int c[4]; int sum = 0;
        #pragma unroll
        for (int i = 0; i < 4; ++i) {
            int bb = 4 * t + i;
            c[i] = (bb < nbuk) ? lcnt[bb] : 0;
            sum += c[i];
        }
        tsum[t] = sum; __syncthreads();
        int run = sum;
        for (int off = 1; off < 256; off <<= 1) {
            int a = (t >= off) ? tsum[t - off] : 0;
            __syncthreads(); tsum[t] += a; __syncthreads();
        }
        int excl = tsum[t] - run;
        #pragma unroll
        for (int i = 0; i < 4; ++i) {
            int bb = 4 * t + i;
            if (bb < nbuk) {
                lcur[bb] = excl;
                int res = (c[i] > 0) ? atomicAdd(&gcur[bb], c[i]) : 0;
                lcnt[bb] = res - excl;         // delta: local slot -> global index
                excl += c[i];
            }
        }
        __syncthreads();
        // place records into LDS grouped by bucket
        for (int j = s + t; j < e; j += 256) {
            int r = row[j], cc = col[j];
            int b = cc >> 7;
            int slot = atomicAdd(&lcur[b], 1);
            recs[slot] = make_uint2((unsigned)r | ((unsigned)(cc & (NPB - 1)) << 17),
                                    __float_as_uint(wt[j]));
            bks[slot] = (unsigned short)b;
        }
        __syncthreads();
        // flush in slot order -> contiguous run per bucket (coalesced)
        for (int i = t; i < n; i += 256) {
            int b = bks[i];
            sedge[lcnt[b] + i] = recs[i];
        }
    } else {
        // fallback: per-record reservation (not hit at E=3.2M)
        for (int j = s + t; j < e; j += 256) {
            int r = row[j], cc = col[j];
            int b = cc >> 7;
            int pos = atomicAdd(&gcur[b], 1);
            sedge[pos] = make_uint2((unsigned)r | ((unsigned)(cc & (NPB - 1)) << 17),
                                    __float_as_uint(wt[j]));
        }
    }
}

// ---------- Phase D: per-bucket counting sort (LDS-staged) -> per-node CSR + dis ----------
__global__ void k_sort(const uint2* __restrict__ sedge, const int* __restrict__ base,
                       uint2* __restrict__ sedge2, int* __restrict__ rowptr,
                       float* __restrict__ dis, int N, int nbuk) {
    __shared__ uint2 ebuf[SCAP];
    __shared__ int   cnt[NPB];
    __shared__ float wdeg[NPB];
    __shared__ int   scn[NPB];
    __shared__ int   cur[NPB];
    int b = blockIdx.x, t = threadIdx.x;
    if (t < NPB) { cnt[t] = 0; wdeg[t] = 1.0f; }   // self-loop weight 1
    __syncthreads();
    int s = base[b], e = base[b + 1];
    int n = e - s;
    bool fit = (n <= SCAP);
    for (int j = s + t; j < e; j += 256) {
        uint2 rec = sedge[j];
        if (fit) ebuf[j - s] = rec;
        int lc = rec.x >> 17;
        atomicAdd(&cnt[lc], 1);
        atomicAdd(&wdeg[lc], __uint_as_float(rec.y));
    }
    __syncthreads();
    if (t < NPB) scn[t] = cnt[t];
    __syncthreads();
    for (int off = 1; off < NPB; off <<= 1) {
        int a = (t < NPB && t >= off) ? scn[t - off] : 0;
        __syncthreads();
        if (t < NPB) scn[t] += a;
        __syncthreads();
    }
    if (t < NPB) {
        int excl = scn[t] - cnt[t];
        cur[t] = s + excl;
        int nn = b * NPB + t;
        if (nn < N) {
            rowptr[nn] = s + excl;
            dis[nn] = rsqrtf(wdeg[t]);
        }
    }
    __syncthreads();
    for (int i = t; i < n; i += 256) {
        uint2 rec = fit ? ebuf[i] : sedge[s + i];
        int lc = rec.x >> 17;
        int pos = atomicAdd(&cur[lc], 1);
        sedge2[pos] = make_uint2(rec.x & 0x1FFFF, rec.y);   // y = raw w (dis folded into features)
    }
    if (b == nbuk - 1 && t == 0) rowptr[N] = e;
}

// ---------- h1_hat = dis * (x @ W1) via 16x16x32 bf16 MFMA, hi/lo trunc split ----------
__global__ void k_xw1_mfma(const float* __restrict__ x, const float* __restrict__ W1,
                           const float* __restrict__ dis, float* __restrict__ h1,
                           int N, int nTiles) {
    __shared__ unsigned short wh[HID][F_IN + 8];
    __shared__ unsigned short wl[HID][F_IN + 8];
    for (int f = threadIdx.x; f < F_IN * HID; f += 256) {
        int k = f >> 4, h = f & 15;
        float v = W1[f];
        unsigned short hhi = bf16_rne(v);
        float rem = v - bf16_f32(hhi);
        wh[h][k] = hhi;
        wl[h][k] = (unsigned short)(__float_as_uint(rem) >> 16);
    }
    __syncthreads();

    int wave = threadIdx.x >> 6;
    int lane = threadIdx.x & 63;
    int tile = blockIdx.x * 4 + wave;
    if (tile >= nTiles) return;

    int m    = lane & 15;
    int quad = lane >> 4;
    int node = tile * 16 + m;
    if (node >= N) node = N - 1;
    const float* xr = x + (size_t)node * F_IN;

    floatx4 acc = {0.f, 0.f, 0.f, 0.f};

    #pragma unroll 4
    for (int s = 0; s < F_IN / 32; ++s) {
        int k0 = s * 32 + quad * 8;
        float4 v0 = *(const float4*)(xr + k0);
        float4 v1 = *(const float4*)(xr + k0 + 4);
        float xv[8] = {v0.x, v0.y, v0.z, v0.w, v1.x, v1.y, v1.z, v1.w};
        short8 ah, al;
        #pragma unroll
        for (int j = 0; j < 8; ++j) {
            unsigned u = __float_as_uint(xv[j]);
            ah[j] = (short)(u >> 16);                       // truncated hi
            float rem = xv[j] - __uint_as_float(u & 0xffff0000u);
            al[j] = (short)(__float_as_uint(rem) >> 16);    // truncated lo
        }
        short8 bh = *(const short8*)&wh[m][k0];
        short8 bl = *(const short8*)&wl[m][k0];
        acc = __builtin_amdgcn_mfma_f32_16x16x32_bf16(ah, bh, acc, 0, 0, 0);
        acc = __builtin_amdgcn_mfma_f32_16x16x32_bf16(ah, bl, acc, 0, 0, 0);
        acc = __builtin_amdgcn_mfma_f32_16x16x32_bf16(al, bh, acc, 0, 0, 0);
    }

    int h = lane & 15;
    #pragma unroll
    for (int r = 0; r < 4; ++r) {
        int nrow = tile * 16 + quad * 4 + r;
        if (nrow < N) h1[(size_t)nrow * HID + h] = dis[nrow] * acc[r];
    }
}

// ---------- atomic-free aggregation: 16-lane group per node ----------
// src holds PRE-SCALED features hhat[r] = dis[r]*h[r].
// v = dis[c]*(sum_e w_e*hhat[r] + hhat[c]) (+bias, relu); postscale multiplies
// by dis[c] again to produce the next layer's hhat directly.
__global__ void k_agg2(const uint2* __restrict__ sedge2, const int* __restrict__ rowptr,
                       const float* __restrict__ dis, const float* __restrict__ src,
                       const float* __restrict__ bias, float* __restrict__ dst,
                       int N, int relu, int postscale) {
    int g = (blockIdx.x * 256 + threadIdx.x) >> 4;   // node
    int h = threadIdx.x & 15;
    if (g >= N) return;
    int e0 = rowptr[g], e1 = rowptr[g + 1];
    float acc = 0.f;
    int j = e0;
    for (; j + 4 <= e1; j += 4) {
        uint2 r0 = sedge2[j + 0];
        uint2 r1 = sedge2[j + 1];
        uint2 r2 = sedge2[j + 2];
        uint2 r3 = sedge2[j + 3];
        float v0 = src[(size_t)r0.x * HID + h];
        float v1 = src[(size_t)r1.x * HID + h];
        float v2 = src[(size_t)r2.x * HID + h];
        float v3 = src[(size_t)r3.x * HID + h];
        acc = fmaf(__uint_as_float(r0.y), v0, acc);
        acc = fmaf(__uint_as_float(r1.y), v1, acc);
        acc = fmaf(__uint_as_float(r2.y), v2, acc);
        acc = fmaf(__uint_as_float(r3.y), v3, acc);
    }
    for (; j < e1; ++j) {
        uint2 r = sedge2[j];
        acc = fmaf(__uint_as_float(r.y), src[(size_t)r.x * HID + h], acc);
    }
    float d = dis[g];
    float v = d * (acc + src[(size_t)g * HID + h]);
    if (bias) v += bias[h];
    if (relu) v = v > 0.f ? v : 0.f;
    if (postscale) v *= d;
    dst[(size_t)g * HID + h] = v;
}

// ---------- out = log_softmax(z2 @ W2 + b2) ----------
__global__ void k_final(const float* __restrict__ B, const float* __restrict__ W2,
                        const float* __restrict__ b2, float* __restrict__ out, int N) {
    __shared__ float w2s[HID * NCLS];
    __shared__ float b2s[NCLS];
    for (int f = threadIdx.x; f < HID * NCLS; f += 256) w2s[f] = W2[f];
    if (threadIdx.x < NCLS) b2s[threadIdx.x] = b2[threadIdx.x];
    __syncthreads();
    int nd = blockIdx.x * 256 + threadIdx.x;
    if (nd < N) {
        float a[HID];
        const float4* ap = (const float4*)(B + (size_t)nd * HID);
        #pragma unroll
        for (int q = 0; q < 4; ++q) {
            float4 v = ap[q];
            a[q * 4 + 0] = v.x; a[q * 4 + 1] = v.y;
            a[q * 4 + 2] = v.z; a[q * 4 + 3] = v.w;
        }
        float y[NCLS];
        #pragma unroll
        for (int c = 0; c < NCLS; ++c) y[c] = b2s[c];
        #pragma unroll
        for (int hh = 0; hh < HID; ++hh) {
            float av = a[hh];
            #pragma unroll
            for (int c = 0; c < NCLS; ++c) y[c] = fmaf(av, w2s[hh * NCLS + c], y[c]);
        }
        float m = y[0];
        #pragma unroll
        for (int c = 1; c < NCLS; ++c) m = fmaxf(m, y[c]);
        float sum = 0.f;
        #pragma unroll
        for (int c = 0; c < NCLS; ++c) sum += expf(y[c] - m);
        float bse = m + logf(sum);
        float* op = out + (size_t)nd * NCLS;
        #pragma unroll
        for (int c = 0; c < NCLS; ++c) op[c] = y[c] - bse;
    }
}

// ---------- launch ----------
extern "C" void kernel_launch(void* const* d_in, const int* in_sizes, int n_in,
                              void* d_out, int out_size, void* d_ws, size_t ws_size,
                              hipStream_t stream) {
    const float* x  = (const float*)d_in[0];
    const int*   ei = (const int*)d_in[1];
    const float* ew = (const float*)d_in[2];
    const float* W1 = (const float*)d_in[3];
    const float* b1 = (const float*)d_in[4];
    const float* W2 = (const float*)d_in[5];
    const float* b2 = (const float*)d_in[6];
    float* out = (float*)d_out;

    int N = in_sizes[0] / F_IN;      // 100000
    int E = in_sizes[2];             // 3200000
    const int* row = ei;
    const int* col = ei + E;

    int nbuk  = (N + NPB - 1) / NPB;         // 782
    int chunk = (E + NPW - 1) / NPW;         // 3125

    // workspace layout
    char* w = (char*)d_ws;
    uint2* sedge  = (uint2*)w;                     size_t off = (size_t)E * 8;
    uint2* sedge2 = (uint2*)(w + off);             off += (size_t)E * 8;
    float* A      = (float*)(w + off);             off += (size_t)N * HID * 4;
    float* Bb     = (float*)(w + off);             off += (size_t)N * HID * 4;
    float* dis    = (float*)(w + off);             off += (size_t)N * 4;
    int*   rowptr = (int*)(w + off);               off += (size_t)(N + 1) * 4;
    int*   tot    = (int*)(w + off);               off += (size_t)nbuk * 4;
    int*   base   = (int*)(w + off);               off += (size_t)(nbuk + 1) * 4;
    int*   gcur   = (int*)(w + off);               off += (size_t)nbuk * 4;

    dim3 blk(256);

    // partition build (bucket level) via reservation scheme
    k_zero<<<dim3((nbuk + 255) / 256), blk, 0, stream>>>(tot, nbuk);
    k_hist<<<dim3(NPW), blk, 0, stream>>>(col, tot, E, chunk, nbuk);
    k_base<<<dim3(1), dim3(1024), 0, stream>>>(tot, base, gcur, nbuk, E);
    k_part<<<dim3(NPW), blk, 0, stream>>>(row, col, ew, gcur, sedge, E, chunk, nbuk);

    // node-level CSR + dis (weights stay raw; dis folded into features)
    k_sort<<<dim3(nbuk), blk, 0, stream>>>(sedge, base, sedge2, rowptr, dis, N, nbuk);

    // h1_hat = dis * (x @ W1) (MFMA)
    int nTiles = (N + 15) / 16;
    int gT = (nTiles + 3) / 4;
    k_xw1_mfma<<<dim3(gT), blk, 0, stream>>>(x, W1, dis, A, N, nTiles);

    // pass 1: h2_hat = dis*relu(dis*(agg+self)+b1) ; pass 2: z2 = dis*(agg+self)
    int gA = (N * HID + 255) / 256;
    k_agg2<<<dim3(gA), blk, 0, stream>>>(sedge2, rowptr, dis, A, b1, Bb, N, 1, 1);
    k_agg2<<<dim3(gA), blk, 0, stream>>>(sedge2, rowptr, dis, Bb, (const float*)nullptr, A, N, 0, 0);

    // out
    k_final<<<dim3((N + 255) / 256), blk, 0, stream>>>(A, W2, b2, out, N);
}

// Round 6
// 580.458 us; speedup vs baseline: 2.0844x; 1.0666x over previous
//
#include <hip/hip_runtime.h>
#include <math.h>

#define F_IN 512
#define HID  16
#define NCLS 40
#define NPB  128      // nodes per bucket (c >> 7)
#define NPW  2048     // partition workgroups
#define MAXBUK 1024
#define CAP  5120     // fixed slot capacity per bucket (mean 4096, +16 sigma)
#define SCAP 4608     // max edges per bucket staged in LDS in k_sort

typedef __attribute__((ext_vector_type(8))) short short8;
typedef __attribute__((ext_vector_type(4))) float floatx4;

// ---------- bf16 helpers ----------
__device__ __forceinline__ unsigned short bf16_rne(float f) {
    unsigned u = __float_as_uint(f);
    u += 0x7fffu + ((u >> 16) & 1u);
    return (unsigned short)(u >> 16);
}
__device__ __forceinline__ float bf16_f32(unsigned short s) {
    return __uint_as_float(((unsigned)s) << 16);
}

// ---------- init per-bucket reservation cursors: gcur[b] = b*CAP ----------
__global__ void k_zero(int* __restrict__ gcur, int nbuk) {
    int i = blockIdx.x * 256 + threadIdx.x;
    if (i < nbuk) gcur[i] = i * CAP;
}

// ---------- Phase C: single-pass partition into fixed-capacity buckets ----------
// Per chunk: LDS hist -> one gcur reservation per nonempty bucket -> direct
// global writes at LDS-cursor slots. No staging buffer, no scan: LDS 8 KB ->
// 8 blocks/CU (vs 3 with staging). Writes are short runs into the L2-resident
// bucket region (write scatter absorbed by L2; measured ~2x amplification).
// record: x = r | (local_c << 17), y = bits(w)
__global__ void k_part(const int* __restrict__ row, const int* __restrict__ col,
                       const float* __restrict__ wt, int* __restrict__ gcur,
                       uint2* __restrict__ sedge, int E, int chunk, int nbuk) {
    __shared__ int lcnt[MAXBUK];
    __shared__ int lcur[MAXBUK];
    int t = threadIdx.x;
    int s = blockIdx.x * chunk;
    int e = s + chunk; if (e > E) e = E;
    if (e <= s) return;
    for (int i = t; i < nbuk; i += 256) lcnt[i] = 0;
    __syncthreads();
    // local histogram (col stays L1/L2-hot for the second pass)
    for (int j = s + t; j < e; j += 256)
        atomicAdd(&lcnt[col[j] >> 7], 1);
    __syncthreads();
    // reserve one contiguous run per nonempty bucket
    for (int b = t; b < nbuk; b += 256) {
        int c = lcnt[b];
        lcur[b] = c ? atomicAdd(&gcur[b], c) : 0;
    }
    __syncthreads();
    // place records directly at reserved global slots
    for (int j = s + t; j < e; j += 256) {
        int r = row[j], cc = col[j];
        int b = cc >> 7;
        int slot = atomicAdd(&lcur[b], 1);
        if (slot < (b + 1) * CAP)   // overflow guard (never hit for this input)
            sedge[slot] = make_uint2((unsigned)r | ((unsigned)(cc & (NPB - 1)) << 17),
                                     __float_as_uint(wt[j]));
    }
}

// ---------- Phase D: per-bucket counting sort (LDS-staged) -> per-node (start,end) + dis ----------
__global__ void k_sort(const uint2* __restrict__ sedge, const int* __restrict__ gcur,
                       uint2* __restrict__ sedge2, int2* __restrict__ rowse,
                       float* __restrict__ dis, int N, int nbuk) {
    __shared__ uint2 ebuf[SCAP];
    __shared__ int   cnt[NPB];
    __shared__ float wdeg[NPB];
    __shared__ int   scn[NPB];
    __shared__ int   cur[NPB];
    int b = blockIdx.x, t = threadIdx.x;
    if (t < NPB) { cnt[t] = 0; wdeg[t] = 1.0f; }   // self-loop weight 1
    __syncthreads();
    int s = b * CAP;
    int e = gcur[b];                                // final cursor = base + count
    int n = e - s;
    bool fit = (n <= SCAP);
    for (int j = s + t; j < e; j += 256) {
        uint2 rec = sedge[j];
        if (fit) ebuf[j - s] = rec;
        int lc = rec.x >> 17;
        atomicAdd(&cnt[lc], 1);
        atomicAdd(&wdeg[lc], __uint_as_float(rec.y));
    }
    __syncthreads();
    if (t < NPB) scn[t] = cnt[t];
    __syncthreads();
    for (int off = 1; off < NPB; off <<= 1) {
        int a = (t < NPB && t >= off) ? scn[t - off] : 0;
        __syncthreads();
        if (t < NPB) scn[t] += a;
        __syncthreads();
    }
    if (t < NPB) {
        int excl = scn[t] - cnt[t];
        cur[t] = s + excl;
        int nn = b * NPB + t;
        if (nn < N) {
            rowse[nn] = make_int2(s + excl, s + excl + cnt[t]);
            dis[nn] = rsqrtf(wdeg[t]);
        }
    }
    __syncthreads();
    for (int i = t; i < n; i += 256) {
        uint2 rec = fit ? ebuf[i] : sedge[s + i];
        int lc = rec.x >> 17;
        int pos = atomicAdd(&cur[lc], 1);
        sedge2[pos] = make_uint2(rec.x & 0x1FFFF, rec.y);   // y = raw w (dis folded into features)
    }
}

// ---------- h1_hat = dis * (x @ W1) via 16x16x32 bf16 MFMA, hi/lo trunc split ----------
__global__ void k_xw1_mfma(const float* __restrict__ x, const float* __restrict__ W1,
                           const float* __restrict__ dis, float* __restrict__ h1,
                           int N, int nTiles) {
    __shared__ unsigned short wh[HID][F_IN + 8];
    __shared__ unsigned short wl[HID][F_IN + 8];
    for (int f = threadIdx.x; f < F_IN * HID; f += 256) {
        int k = f >> 4, h = f & 15;
        float v = W1[f];
        unsigned short hhi = bf16_rne(v);
        float rem = v - bf16_f32(hhi);
        wh[h][k] = hhi;
        wl[h][k] = (unsigned short)(__float_as_uint(rem) >> 16);
    }
    __syncthreads();

    int wave = threadIdx.x >> 6;
    int lane = threadIdx.x & 63;
    int tile = blockIdx.x * 4 + wave;
    if (tile >= nTiles) return;

    int m    = lane & 15;
    int quad = lane >> 4;
    int node = tile * 16 + m;
    if (node >= N) node = N - 1;
    const float* xr = x + (size_t)node * F_IN;

    floatx4 acc = {0.f, 0.f, 0.f, 0.f};

    #pragma unroll 4
    for (int s = 0; s < F_IN / 32; ++s) {
        int k0 = s * 32 + quad * 8;
        float4 v0 = *(const float4*)(xr + k0);
        float4 v1 = *(const float4*)(xr + k0 + 4);
        float xv[8] = {v0.x, v0.y, v0.z, v0.w, v1.x, v1.y, v1.z, v1.w};
        short8 ah, al;
        #pragma unroll
        for (int j = 0; j < 8; ++j) {
            unsigned u = __float_as_uint(xv[j]);
            ah[j] = (short)(u >> 16);                       // truncated hi
            float rem = xv[j] - __uint_as_float(u & 0xffff0000u);
            al[j] = (short)(__float_as_uint(rem) >> 16);    // truncated lo
        }
        short8 bh = *(const short8*)&wh[m][k0];
        short8 bl = *(const short8*)&wl[m][k0];
        acc = __builtin_amdgcn_mfma_f32_16x16x32_bf16(ah, bh, acc, 0, 0, 0);
        acc = __builtin_amdgcn_mfma_f32_16x16x32_bf16(ah, bl, acc, 0, 0, 0);
        acc = __builtin_amdgcn_mfma_f32_16x16x32_bf16(al, bh, acc, 0, 0, 0);
    }

    int h = lane & 15;
    #pragma unroll
    for (int r = 0; r < 4; ++r) {
        int nrow = tile * 16 + quad * 4 + r;
        if (nrow < N) h1[(size_t)nrow * HID + h] = dis[nrow] * acc[r];
    }
}

// ---------- atomic-free aggregation: 16-lane group per node ----------
// src holds PRE-SCALED features hhat[r] = dis[r]*h[r].
// v = dis[c]*(sum_e w_e*hhat[r] + hhat[c]) (+bias, relu); postscale multiplies
// by dis[c] again to produce the next layer's hhat directly.
__global__ void k_agg2(const uint2* __restrict__ sedge2, const int2* __restrict__ rowse,
                       const float* __restrict__ dis, const float* __restrict__ src,
                       const float* __restrict__ bias, float* __restrict__ dst,
                       int N, int relu, int postscale) {
    int g = (blockIdx.x * 256 + threadIdx.x) >> 4;   // node
    int h = threadIdx.x & 15;
    if (g >= N) return;
    int2 se = rowse[g];
    int e1 = se.y;
    float acc = 0.f;
    int j = se.x;
    for (; j + 4 <= e1; j += 4) {
        uint2 r0 = sedge2[j + 0];
        uint2 r1 = sedge2[j + 1];
        uint2 r2 = sedge2[j + 2];
        uint2 r3 = sedge2[j + 3];
        float v0 = src[(size_t)r0.x * HID + h];
        float v1 = src[(size_t)r1.x * HID + h];
        float v2 = src[(size_t)r2.x * HID + h];
        float v3 = src[(size_t)r3.x * HID + h];
        acc = fmaf(__uint_as_float(r0.y), v0, acc);
        acc = fmaf(__uint_as_float(r1.y), v1, acc);
        acc = fmaf(__uint_as_float(r2.y), v2, acc);
        acc = fmaf(__uint_as_float(r3.y), v3, acc);
    }
    for (; j < e1; ++j) {
        uint2 r = sedge2[j];
        acc = fmaf(__uint_as_float(r.y), src[(size_t)r.x * HID + h], acc);
    }
    float d = dis[g];
    float v = d * (acc + src[(size_t)g * HID + h]);
    if (bias) v += bias[h];
    if (relu) v = v > 0.f ? v : 0.f;
    if (postscale) v *= d;
    dst[(size_t)g * HID + h] = v;
}

// ---------- out = log_softmax(z2 @ W2 + b2) ----------
__global__ void k_final(const float* __restrict__ B, const float* __restrict__ W2,
                        const float* __restrict__ b2, float* __restrict__ out, int N) {
    __shared__ float w2s[HID * NCLS];
    __shared__ float b2s[NCLS];
    for (int f = threadIdx.x; f < HID * NCLS; f += 256) w2s[f] = W2[f];
    if (threadIdx.x < NCLS) b2s[threadIdx.x] = b2[threadIdx.x];
    __syncthreads();
    int nd = blockIdx.x * 256 + threadIdx.x;
    if (nd < N) {
        float a[HID];
        const float4* ap = (const float4*)(B + (size_t)nd * HID);
        #pragma unroll
        for (int q = 0; q < 4; ++q) {
            float4 v = ap[q];
            a[q * 4 + 0] = v.x; a[q * 4 + 1] = v.y;
            a[q * 4 + 2] = v.z; a[q * 4 + 3] = v.w;
        }
        float y[NCLS];
        #pragma unroll
        for (int c = 0; c < NCLS; ++c) y[c] = b2s[c];
        #pragma unroll
        for (int hh = 0; hh < HID; ++hh) {
            float av = a[hh];
            #pragma unroll
            for (int c = 0; c < NCLS; ++c) y[c] = fmaf(av, w2s[hh * NCLS + c], y[c]);
        }
        float m = y[0];
        #pragma unroll
        for (int c = 1; c < NCLS; ++c) m = fmaxf(m, y[c]);
        float sum = 0.f;
        #pragma unroll
        for (int c = 0; c < NCLS; ++c) sum += expf(y[c] - m);
        float bse = m + logf(sum);
        float* op = out + (size_t)nd * NCLS;
        #pragma unroll
        for (int c = 0; c < NCLS; ++c) op[c] = y[c] - bse;
    }
}

// ---------- launch ----------
extern "C" void kernel_launch(void* const* d_in, const int* in_sizes, int n_in,
                              void* d_out, int out_size, void* d_ws, size_t ws_size,
                              hipStream_t stream) {
    const float* x  = (const float*)d_in[0];
    const int*   ei = (const int*)d_in[1];
    const float* ew = (const float*)d_in[2];
    const float* W1 = (const float*)d_in[3];
    const float* b1 = (const float*)d_in[4];
    const float* W2 = (const float*)d_in[5];
    const float* b2 = (const float*)d_in[6];
    float* out = (float*)d_out;

    int N = in_sizes[0] / F_IN;      // 100000
    int E = in_sizes[2];             // 3200000
    const int* row = ei;
    const int* col = ei + E;

    int nbuk  = (N + NPB - 1) / NPB;         // 782
    int chunk = (E + NPW - 1) / NPW;         // 1563

    // workspace layout
    char* w = (char*)d_ws;
    uint2* sedge  = (uint2*)w;                     size_t off = (size_t)nbuk * CAP * 8;
    uint2* sedge2 = (uint2*)(w + off);             off += (size_t)nbuk * CAP * 8;
    float* A      = (float*)(w + off);             off += (size_t)N * HID * 4;
    float* Bb     = (float*)(w + off);             off += (size_t)N * HID * 4;
    float* dis    = (float*)(w + off);             off += (size_t)N * 4;
    int2*  rowse  = (int2*)(w + off);              off += (size_t)N * 8;
    int*   gcur   = (int*)(w + off);               off += (size_t)nbuk * 4;

    dim3 blk(256);

    // partition build: fixed-capacity buckets, direct reservation scatter
    k_zero<<<dim3((nbuk + 255) / 256), blk, 0, stream>>>(gcur, nbuk);
    k_part<<<dim3(NPW), blk, 0, stream>>>(row, col, ew, gcur, sedge, E, chunk, nbuk);

    // node-level (start,end) + dis (weights stay raw; dis folded into features)
    k_sort<<<dim3(nbuk), blk, 0, stream>>>(sedge, gcur, sedge2, rowse, dis, N, nbuk);

    // h1_hat = dis * (x @ W1) (MFMA)
    int nTiles = (N + 15) / 16;
    int gT = (nTiles + 3) / 4;
    k_xw1_mfma<<<dim3(gT), blk, 0, stream>>>(x, W1, dis, A, N, nTiles);

    // pass 1: h2_hat = dis*relu(dis*(agg+self)+b1) ; pass 2: z2 = dis*(agg+self)
    int gA = (N * HID + 255) / 256;
    k_agg2<<<dim3(gA), blk, 0, stream>>>(sedge2, rowse, dis, A, b1, Bb, N, 1, 1);
    k_agg2<<<dim3(gA), blk, 0, stream>>>(sedge2, rowse, dis, Bb, (const float*)nullptr, A, N, 0, 0);

    // out
    k_final<<<dim3((N + 255) / 256), blk, 0, stream>>>(A, W2, b2, out, N);
}

// Round 7
// 527.686 us; speedup vs baseline: 2.2929x; 1.1000x over previous
//
#include <hip/hip_runtime.h>
#include <math.h>

#define F_IN 512
#define HID  16
#define NCLS 40
#define NPB  128      // nodes per bucket (c >> 7)
#define NSL  8        // slices (= XCDs); slice = bucket / BPS
#define BPS  98       // buckets per slice (ceil(782/8)) -- matches N=100000
#define SLCAP 405504  // slice stream capacity (mean 400K, +9 sigma)
#define CAP  4608     // fixed slot capacity per bucket (mean 4096, +8 sigma)
#define NPW  2048     // k_split workgroups
#define CPW2 256      // chunks per slice in k_part2
#define CH1  1600     // max edges per chunk staged in LDS

typedef __attribute__((ext_vector_type(8))) short short8;
typedef __attribute__((ext_vector_type(4))) float floatx4;

// ---------- bf16 helpers ----------
__device__ __forceinline__ unsigned short bf16_rne(float f) {
    unsigned u = __float_as_uint(f);
    u += 0x7fffu + ((u >> 16) & 1u);
    return (unsigned short)(u >> 16);
}
__device__ __forceinline__ float bf16_f32(unsigned short s) {
    return __uint_as_float(((unsigned)s) << 16);
}

// ---------- init cursors: gcur[b] = b*CAP (bucket), scur[s] = s*SLCAP (slice) ----------
__global__ void k_zero(int* __restrict__ gcur, int* __restrict__ scur, int nbuk) {
    int i = blockIdx.x * 256 + threadIdx.x;
    if (i < nbuk) gcur[i] = i * CAP;
    if (i < NSL) scur[i] = i * SLCAP;
}

// ---------- Level 1: partition edges into 8 slice streams (coalesced runs) ----------
// record: x = r(17b) | local_c(7b)<<17 | bucket_in_slice(7b)<<24, y = bits(w)
__global__ void k_split(const int* __restrict__ row, const int* __restrict__ col,
                        const float* __restrict__ wt, int* __restrict__ scur,
                        uint2* __restrict__ gstr, int E, int chunk) {
    __shared__ uint2 recs[CH1];
    __shared__ unsigned char bks[CH1];
    __shared__ int cnt8[NSL], cur8[NSL], delta8[NSL];
    int t = threadIdx.x;
    int s0 = blockIdx.x * chunk;
    int e0 = s0 + chunk; if (e0 > E) e0 = E;
    int n = e0 - s0;
    if (n <= 0) return;

    if (n <= CH1) {
        if (t < NSL) cnt8[t] = 0;
        __syncthreads();
        for (int j = s0 + t; j < e0; j += 256)
            atomicAdd(&cnt8[(col[j] >> 7) / BPS], 1);
        __syncthreads();
        if (t == 0) {
            int run = 0;
            for (int i = 0; i < NSL; ++i) { cur8[i] = run; run += cnt8[i]; }
        }
        __syncthreads();
        if (t < NSL) {
            int c = cnt8[t];
            int start = cur8[t];
            int res = c ? atomicAdd(&scur[t], c) : 0;
            delta8[t] = res - start;
        }
        __syncthreads();
        for (int j = s0 + t; j < e0; j += 256) {
            int r = row[j], cc = col[j];
            int b = cc >> 7;
            int sl = b / BPS;
            int bsl = b - sl * BPS;
            int slot = atomicAdd(&cur8[sl], 1);
            recs[slot] = make_uint2((unsigned)r | ((unsigned)(cc & (NPB - 1)) << 17) |
                                    ((unsigned)bsl << 24),
                                    __float_as_uint(wt[j]));
            bks[slot] = (unsigned char)sl;
        }
        __syncthreads();
        // flush: ~n/8-record contiguous runs per slice (coalesced)
        for (int i = t; i < n; i += 256) {
            int sl = bks[i];
            int dst = delta8[sl] + i;
            if ((unsigned)(dst - sl * SLCAP) < SLCAP) gstr[dst] = recs[i];
        }
    } else {
        // fallback: per-edge reservation (not hit at E=3.2M)
        for (int j = s0 + t; j < e0; j += 256) {
            int r = row[j], cc = col[j];
            int b = cc >> 7;
            int sl = b / BPS;
            int bsl = b - sl * BPS;
            int pos = atomicAdd(&scur[sl], 1);
            if ((unsigned)(pos - sl * SLCAP) < SLCAP)
                gstr[pos] = make_uint2((unsigned)r | ((unsigned)(cc & (NPB - 1)) << 17) |
                                       ((unsigned)bsl << 24),
                                       __float_as_uint(wt[j]));
        }
    }
}

// ---------- Level 2: per-slice counting scatter into 3.6 MB L2-resident window ----------
// bid%8 = slice -> lands on the XCD that owns sedge[slice] (locality heuristic only).
__global__ void k_part2(const uint2* __restrict__ gstr, const int* __restrict__ scur,
                        int* __restrict__ gcur, uint2* __restrict__ sedge, int nbuk) {
    __shared__ uint2 recs[CH1];
    __shared__ unsigned char bks[CH1];
    __shared__ int lcnt[BPS], lcur[BPS], ldelta[BPS];
    __shared__ int scn[128];
    int t = threadIdx.x;
    int sl = blockIdx.x & 7;
    int ci = blockIdx.x >> 3;          // 0..CPW2-1
    int sbeg = sl * SLCAP;
    int send = scur[sl];               // final cursor = base + slice count
    int ns = send - sbeg;
    int ch = (ns + CPW2 - 1) / CPW2;
    int s0 = sbeg + ci * ch;
    int e0 = s0 + ch; if (e0 > send) e0 = send;
    int n = e0 - s0;
    if (n <= 0) return;
    for (int i = t; i < BPS; i += 256) lcnt[i] = 0;
    __syncthreads();
    for (int j = s0 + t; j < e0; j += 256)
        atomicAdd(&lcnt[gstr[j].x >> 24], 1);
    __syncthreads();
    if (t < 128) scn[t] = (t < BPS) ? lcnt[t] : 0;
    __syncthreads();
    for (int off = 1; off < 128; off <<= 1) {
        int a = (t < 128 && t >= off) ? scn[t - off] : 0;
        __syncthreads();
        if (t < 128) scn[t] += a;
        __syncthreads();
    }
    if (t < BPS) {
        int c = lcnt[t];
        int start = scn[t] - c;
        lcur[t] = start;
        int res = c ? atomicAdd(&gcur[sl * BPS + t], c) : 0;
        ldelta[t] = res - start;
    }
    __syncthreads();
    for (int j = s0 + t; j < e0; j += 256) {
        uint2 rec = gstr[j];
        int bsl = rec.x >> 24;
        int slot = atomicAdd(&lcur[bsl], 1);
        recs[slot] = rec;
        bks[slot] = (unsigned char)bsl;
    }
    __syncthreads();
    // flush ~128B runs per bucket into the slice's L2-resident window
    for (int i = t; i < n; i += 256) {
        int bsl = bks[i];
        int gb = sl * BPS + bsl;
        int dst = ldelta[bsl] + i;
        if (dst < (gb + 1) * CAP) {
            uint2 rr = recs[i];
            rr.x &= 0x00FFFFFFu;
            sedge[dst] = rr;
        }
    }
}

// ---------- per-bucket counting sort (XCD-pinned, LDS-staged) -> (start,end) + dis ----------
__global__ void k_sort(const uint2* __restrict__ sedge, const int* __restrict__ gcur,
                       uint2* __restrict__ sedge2, int2* __restrict__ rowse,
                       float* __restrict__ dis, int N, int nbuk) {
    __shared__ uint2 ebuf[CAP];
    __shared__ int   cnt[NPB];
    __shared__ float wdeg[NPB];
    __shared__ int   scn[NPB];
    __shared__ int   cur[NPB];
    int sl = blockIdx.x & 7;
    int bi = blockIdx.x >> 3;
    int b = sl * BPS + bi;
    if (bi >= BPS || b >= nbuk) return;
    int t = threadIdx.x;
    if (t < NPB) { cnt[t] = 0; wdeg[t] = 1.0f; }   // self-loop weight 1
    __syncthreads();
    int s = b * CAP;
    int e = gcur[b];                                // final cursor = base + count
    int n = e - s;
    for (int j = s + t; j < e; j += 256) {
        uint2 rec = sedge[j];
        ebuf[j - s] = rec;
        int lc = rec.x >> 17;
        atomicAdd(&cnt[lc], 1);
        atomicAdd(&wdeg[lc], __uint_as_float(rec.y));
    }
    __syncthreads();
    if (t < NPB) scn[t] = cnt[t];
    __syncthreads();
    for (int off = 1; off < NPB; off <<= 1) {
        int a = (t < NPB && t >= off) ? scn[t - off] : 0;
        __syncthreads();
        if (t < NPB) scn[t] += a;
        __syncthreads();
    }
    if (t < NPB) {
        int excl = scn[t] - cnt[t];
        cur[t] = s + excl;
        int nn = b * NPB + t;
        if (nn < N) {
            rowse[nn] = make_int2(s + excl, s + excl + cnt[t]);
            dis[nn] = rsqrtf(wdeg[t]);
        }
    }
    __syncthreads();
    for (int i = t; i < n; i += 256) {
        uint2 rec = ebuf[i];
        int lc = rec.x >> 17;
        int pos = atomicAdd(&cur[lc], 1);
        sedge2[pos] = make_uint2(rec.x & 0x1FFFF, rec.y);   // y = raw w (dis folded into features)
    }
}

// ---------- h1_hat = dis * (x @ W1) via 16x16x32 bf16 MFMA, hi/lo trunc split ----------
__global__ void k_xw1_mfma(const float* __restrict__ x, const float* __restrict__ W1,
                           const float* __restrict__ dis, float* __restrict__ h1,
                           int N, int nTiles) {
    __shared__ unsigned short wh[HID][F_IN + 8];
    __shared__ unsigned short wl[HID][F_IN + 8];
    for (int f = threadIdx.x; f < F_IN * HID; f += 256) {
        int k = f >> 4, h = f & 15;
        float v = W1[f];
        unsigned short hhi = bf16_rne(v);
        float rem = v - bf16_f32(hhi);
        wh[h][k] = hhi;
        wl[h][k] = (unsigned short)(__float_as_uint(rem) >> 16);
    }
    __syncthreads();

    int wave = threadIdx.x >> 6;
    int lane = threadIdx.x & 63;
    int tile = blockIdx.x * 4 + wave;
    if (tile >= nTiles) return;

    int m    = lane & 15;
    int quad = lane >> 4;
    int node = tile * 16 + m;
    if (node >= N) node = N - 1;
    const float* xr = x + (size_t)node * F_IN;

    floatx4 acc = {0.f, 0.f, 0.f, 0.f};

    #pragma unroll 4
    for (int s = 0; s < F_IN / 32; ++s) {
        int k0 = s * 32 + quad * 8;
        float4 v0 = *(const float4*)(xr + k0);
        float4 v1 = *(const float4*)(xr + k0 + 4);
        float xv[8] = {v0.x, v0.y, v0.z, v0.w, v1.x, v1.y, v1.z, v1.w};
        short8 ah, al;
        #pragma unroll
        for (int j = 0; j < 8; ++j) {
            unsigned u = __float_as_uint(xv[j]);
            ah[j] = (short)(u >> 16);                       // truncated hi
            float rem = xv[j] - __uint_as_float(u & 0xffff0000u);
            al[j] = (short)(__float_as_uint(rem) >> 16);    // truncated lo
        }
        short8 bh = *(const short8*)&wh[m][k0];
        short8 bl = *(const short8*)&wl[m][k0];
        acc = __builtin_amdgcn_mfma_f32_16x16x32_bf16(ah, bh, acc, 0, 0, 0);
        acc = __builtin_amdgcn_mfma_f32_16x16x32_bf16(ah, bl, acc, 0, 0, 0);
        acc = __builtin_amdgcn_mfma_f32_16x16x32_bf16(al, bh, acc, 0, 0, 0);
    }

    int h = lane & 15;
    #pragma unroll
    for (int r = 0; r < 4; ++r) {
        int nrow = tile * 16 + quad * 4 + r;
        if (nrow < N) h1[(size_t)nrow * HID + h] = dis[nrow] * acc[r];
    }
}

// ---------- atomic-free aggregation: 16-lane group per node (XCD-pinned) ----------
// src holds PRE-SCALED features hhat[r] = dis[r]*h[r].
// v = dis[c]*(sum_e w_e*hhat[r] + hhat[c]) (+bias, relu); postscale multiplies
// by dis[c] again to produce the next layer's hhat directly.
__global__ void k_agg2(const uint2* __restrict__ sedge2, const int2* __restrict__ rowse,
                       const float* __restrict__ dis, const float* __restrict__ src,
                       const float* __restrict__ bias, float* __restrict__ dst,
                       int N, int nbuk, int relu, int postscale) {
    int sl  = blockIdx.x & 7;
    int loc = blockIdx.x >> 3;          // 0..(BPS*8-1)
    int b   = sl * BPS + (loc >> 3);
    int sub = loc & 7;
    int g = b * NPB + sub * 16 + (threadIdx.x >> 4);   // node
    int h = threadIdx.x & 15;
    if (b >= nbuk || g >= N) return;
    int2 se = rowse[g];
    int e1 = se.y;
    float acc = 0.f;
    int j = se.x;
    for (; j + 4 <= e1; j += 4) {
        uint2 r0 = sedge2[j + 0];
        uint2 r1 = sedge2[j + 1];
        uint2 r2 = sedge2[j + 2];
        uint2 r3 = sedge2[j + 3];
        float v0 = src[(size_t)r0.x * HID + h];
        float v1 = src[(size_t)r1.x * HID + h];
        float v2 = src[(size_t)r2.x * HID + h];
        float v3 = src[(size_t)r3.x * HID + h];
        acc = fmaf(__uint_as_float(r0.y), v0, acc);
        acc = fmaf(__uint_as_float(r1.y), v1, acc);
        acc = fmaf(__uint_as_float(r2.y), v2, acc);
        acc = fmaf(__uint_as_float(r3.y), v3, acc);
    }
    for (; j < e1; ++j) {
        uint2 r = sedge2[j];
        acc = fmaf(__uint_as_float(r.y), src[(size_t)r.x * HID + h], acc);
    }
    float d = dis[g];
    float v = d * (acc + src[(size_t)g * HID + h]);
    if (bias) v += bias[h];
    if (relu) v = v > 0.f ? v : 0.f;
    if (postscale) v *= d;
    dst[(size_t)g * HID + h] = v;
}

// ---------- out = log_softmax(z2 @ W2 + b2) ----------
__global__ void k_final(const float* __restrict__ B, const float* __restrict__ W2,
                        const float* __restrict__ b2, float* __restrict__ out, int N) {
    __shared__ float w2s[HID * NCLS];
    __shared__ float b2s[NCLS];
    for (int f = threadIdx.x; f < HID * NCLS; f += 256) w2s[f] = W2[f];
    if (threadIdx.x < NCLS) b2s[threadIdx.x] = b2[threadIdx.x];
    __syncthreads();
    int nd = blockIdx.x * 256 + threadIdx.x;
    if (nd < N) {
        float a[HID];
        const float4* ap = (const float4*)(B + (size_t)nd * HID);
        #pragma unroll
        for (int q = 0; q < 4; ++q) {
            float4 v = ap[q];
            a[q * 4 + 0] = v.x; a[q * 4 + 1] = v.y;
            a[q * 4 + 2] = v.z; a[q * 4 + 3] = v.w;
        }
        float y[NCLS];
        #pragma unroll
        for (int c = 0; c < NCLS; ++c) y[c] = b2s[c];
        #pragma unroll
        for (int hh = 0; hh < HID; ++hh) {
            float av = a[hh];
            #pragma unroll
            for (int c = 0; c < NCLS; ++c) y[c] = fmaf(av, w2s[hh * NCLS + c], y[c]);
        }
        float m = y[0];
        #pragma unroll
        for (int c = 1; c < NCLS; ++c) m = fmaxf(m, y[c]);
        float sum = 0.f;
        #pragma unroll
        for (int c = 0; c < NCLS; ++c) sum += expf(y[c] - m);
        float bse = m + logf(sum);
        float* op = out + (size_t)nd * NCLS;
        #pragma unroll
        for (int c = 0; c < NCLS; ++c) op[c] = y[c] - bse;
    }
}

// ---------- launch ----------
extern "C" void kernel_launch(void* const* d_in, const int* in_sizes, int n_in,
                              void* d_out, int out_size, void* d_ws, size_t ws_size,
                              hipStream_t stream) {
    const float* x  = (const float*)d_in[0];
    const int*   ei = (const int*)d_in[1];
    const float* ew = (const float*)d_in[2];
    const float* W1 = (const float*)d_in[3];
    const float* b1 = (const float*)d_in[4];
    const float* W2 = (const float*)d_in[5];
    const float* b2 = (const float*)d_in[6];
    float* out = (float*)d_out;

    int N = in_sizes[0] / F_IN;      // 100000
    int E = in_sizes[2];             // 3200000
    const int* row = ei;
    const int* col = ei + E;

    int nbuk  = (N + NPB - 1) / NPB;         // 782
    int chunk = (E + NPW - 1) / NPW;         // 1563

    // workspace layout
    char* w = (char*)d_ws;
    uint2* gstr   = (uint2*)w;                     size_t off = (size_t)NSL * SLCAP * 8;
    uint2* sedge  = (uint2*)(w + off);             off += (size_t)nbuk * CAP * 8;
    uint2* sedge2 = (uint2*)(w + off);             off += (size_t)nbuk * CAP * 8;
    float* A      = (float*)(w + off);             off += (size_t)N * HID * 4;
    float* Bb     = (float*)(w + off);             off += (size_t)N * HID * 4;
    float* dis    = (float*)(w + off);             off += (size_t)N * 4;
    int2*  rowse  = (int2*)(w + off);              off += (size_t)N * 8;
    int*   gcur   = (int*)(w + off);               off += (size_t)nbuk * 4;
    int*   scur   = (int*)(w + off);               off += (size_t)NSL * 4;

    dim3 blk(256);

    // two-level partition: slice streams (coalesced) -> L2-resident bucket scatter
    k_zero<<<dim3((nbuk + 255) / 256), blk, 0, stream>>>(gcur, scur, nbuk);
    k_split<<<dim3(NPW), blk, 0, stream>>>(row, col, ew, scur, gstr, E, chunk);
    k_part2<<<dim3(NSL * CPW2), blk, 0, stream>>>(gstr, scur, gcur, sedge, nbuk);

    // node-level (start,end) + dis (weights stay raw; dis folded into features)
    k_sort<<<dim3(NSL * BPS), blk, 0, stream>>>(sedge, gcur, sedge2, rowse, dis, N, nbuk);

    // h1_hat = dis * (x @ W1) (MFMA)
    int nTiles = (N + 15) / 16;
    int gT = (nTiles + 3) / 4;
    k_xw1_mfma<<<dim3(gT), blk, 0, stream>>>(x, W1, dis, A, N, nTiles);

    // pass 1: h2_hat = dis*relu(dis*(agg+self)+b1) ; pass 2: z2 = dis*(agg+self)
    k_agg2<<<dim3(NSL * BPS * 8), blk, 0, stream>>>(sedge2, rowse, dis, A, b1, Bb, N, nbuk, 1, 1);
    k_agg2<<<dim3(NSL * BPS * 8), blk, 0, stream>>>(sedge2, rowse, dis, Bb, (const float*)nullptr, A, N, nbuk, 0, 0);

    // out
    k_final<<<dim3((N + 255) / 256), blk, 0, stream>>>(A, W2, b2, out, N);
}